// Round 16
// baseline (1017.973 us; speedup 1.0000x reference)
//
#include <hip/hip_runtime.h>

// SimpleMTP: 3 sequential MTP heads on MI355X.
// f16 MFMA everywhere heavy; f32 residual/norms.
// Logits: BM=512 x BN=128 tile (B re-read 24x -> 12x, trio-pair XCD mapping
//   -> each B panel read by one XCD), BK=32 3-slot ring distance-2,
//   vmcnt(5)/tile counted wait, 2 fine phases, chunk-XOR LDS swizzle.
// Small GEMMs: r12 gemm_sm verbatim (64x64, 3-buffer depth-2).
// Wv/Wo fused into Wvo = Wo@Wv (precomputed per call).

#define NPOS   509
#define MROWS  2036
#define MPAD   2048
#define DMODEL 1024

typedef _Float16 f16;
typedef _Float16 f16x8 __attribute__((ext_vector_type(8)));
typedef _Float16 f16x4 __attribute__((ext_vector_type(4)));
typedef float    f32x4 __attribute__((ext_vector_type(4)));

#define MFMA16(a, b, c) __builtin_amdgcn_mfma_f32_16x16x32_f16(a, b, c, 0, 0, 0)
#define VM0   asm volatile("s_waitcnt vmcnt(0)" ::: "memory")
#define VM2   asm volatile("s_waitcnt vmcnt(2)" ::: "memory")
#define VM5   asm volatile("s_waitcnt vmcnt(5)" ::: "memory")
#define LGKM0 asm volatile("s_waitcnt lgkmcnt(0)" ::: "memory")
#define SCHED0 __builtin_amdgcn_sched_barrier(0)
#define BAR   asm volatile("s_barrier" ::: "memory")

__device__ __forceinline__ void gld_lds16(const void* g, void* l) {
  __builtin_amdgcn_global_load_lds(
      (const __attribute__((address_space(1))) void*)g,
      (__attribute__((address_space(3))) void*)l, 16, 0, 0);
}

// ---------------- f32 -> f16 convert: embed ----------------
__global__ __launch_bounds__(256) void conv_f32_f16(const float* __restrict__ src,
                                                    f16* __restrict__ dst, long n) {
  long i = ((long)blockIdx.x * 256 + threadIdx.x) * 8;
  if (i + 8 <= n) {
    float4 a = *(const float4*)(src + i);
    float4 b = *(const float4*)(src + i + 4);
    f16x8 o = {(f16)a.x, (f16)a.y, (f16)a.z, (f16)a.w,
               (f16)b.x, (f16)b.y, (f16)b.z, (f16)b.w};
    *(f16x8*)(dst + i) = o;
  }
}

// ---------------- batched weight conversion (12 tensors) ----------------
struct ConvArgs { const float* s[12]; f16* d[12]; long n[12]; };
__global__ __launch_bounds__(256) void conv_many(ConvArgs a) {
  int t = blockIdx.y;
  long i = ((long)blockIdx.x * 256 + threadIdx.x) * 8;
  if (i + 8 <= a.n[t]) {
    const float* src = a.s[t];
    float4 x = *(const float4*)(src + i);
    float4 y = *(const float4*)(src + i + 4);
    f16x8 o = {(f16)x.x, (f16)x.y, (f16)x.z, (f16)x.w,
               (f16)y.x, (f16)y.y, (f16)y.z, (f16)y.w};
    *(f16x8*)(a.d[t] + i) = o;
  }
}

// ---------------- batched 1024x1024 transpose f32->f16 (Wv -> WvT) ----------------
struct TpArgs { const float* s[3]; f16* d[3]; };
__global__ __launch_bounds__(256) void transpose3(TpArgs a) {
  __shared__ float t[32][33];
  int h = blockIdx.z;
  int bx = blockIdx.x * 32, by = blockIdx.y * 32;
  int tx = threadIdx.x & 31, ty = threadIdx.x >> 5;
  const float* src = a.s[h];
  f16* dst = a.d[h];
  #pragma unroll
  for (int r = 0; r < 32; r += 8)
    t[ty + r][tx] = src[(long)(by + ty + r) * 1024 + bx + tx];
  __syncthreads();
  #pragma unroll
  for (int r = 0; r < 32; r += 8)
    dst[(long)(bx + ty + r) * 1024 + by + tx] = (f16)t[tx][ty + r];
}

// ---------------- bvo = Wo @ bv + bo (batched over heads) ----------------
struct BvoArgs { const float* Wo[3]; const float* bv[3]; const float* bo[3]; float* out[3]; };
__global__ __launch_bounds__(64) void make_bvo3(BvoArgs a) {
  int h = blockIdx.y, r = blockIdx.x, l = threadIdx.x;
  const float* Wo = a.Wo[h];
  const float* bv = a.bv[h];
  float s = 0.0f;
  for (int k = l; k < 1024; k += 64) s += Wo[(long)r * 1024 + k] * bv[k];
  #pragma unroll
  for (int off = 32; off > 0; off >>= 1) s += __shfl_xor(s, off);
  if (l == 0) a.out[h][r] = s + a.bo[h][r];
}

__device__ __forceinline__ float2 block_reduce2(float a, float b) {
  #pragma unroll
  for (int off = 32; off > 0; off >>= 1) {
    a += __shfl_xor(a, off);
    b += __shfl_xor(b, off);
  }
  __shared__ float2 red[4];
  int wv = threadIdx.x >> 6;
  if ((threadIdx.x & 63) == 0) red[wv] = make_float2(a, b);
  __syncthreads();
  float2 r0 = red[0], r1 = red[1], r2 = red[2], r3 = red[3];
  return make_float2(r0.x + r1.x + r2.x + r3.x, r0.y + r1.y + r2.y + r3.y);
}

// ---------------- merged = [rmsnorm(h_prev), rmsnorm(tok)] ----------------
__global__ __launch_bounds__(256) void merge_rms(const float* __restrict__ hprev,
                                                 const float* __restrict__ embed,
                                                 const int* __restrict__ tok,
                                                 f16* __restrict__ merged, int koff,
                                                 int hsel) {
  int r = blockIdx.x;
  int b = r / NPOS, t = r - b * NPOS;
  int tid = threadIdx.x;
  const float* hrow = (hsel >= 0)
      ? embed + (long)tok[b * 512 + t + hsel] * DMODEL
      : hprev + (long)r * DMODEL;
  float4 hv = ((const float4*)hrow)[tid];
  float4 tv = ((const float4*)(embed + (long)tok[b * 512 + t + koff] * DMODEL))[tid];
  float sh = hv.x * hv.x + hv.y * hv.y + hv.z * hv.z + hv.w * hv.w;
  float st = tv.x * tv.x + tv.y * tv.y + tv.z * tv.z + tv.w * tv.w;
  float2 tot = block_reduce2(sh, st);
  float ih = 1.0f / sqrtf(tot.x * (1.0f / DMODEL) + 1e-8f);
  float it = 1.0f / sqrtf(tot.y * (1.0f / DMODEL) + 1e-8f);
  f16x4 oh = {(f16)(hv.x * ih), (f16)(hv.y * ih), (f16)(hv.z * ih), (f16)(hv.w * ih)};
  f16x4 ot = {(f16)(tv.x * it), (f16)(tv.y * it), (f16)(tv.z * it), (f16)(tv.w * it)};
  *(f16x4*)(merged + (long)r * 2048 + tid * 4) = oh;
  *(f16x4*)(merged + (long)r * 2048 + 1024 + tid * 4) = ot;
}

// ---------------- y = LN(x + res) * g + b ----------------
__global__ __launch_bounds__(256) void add_ln(const float* __restrict__ x,
                                              const float* __restrict__ res,
                                              const float* __restrict__ g,
                                              const float* __restrict__ bb,
                                              float* __restrict__ yf,
                                              f16* __restrict__ yh) {
  int r = blockIdx.x, tid = threadIdx.x;
  float4 a = ((const float4*)(x + (long)r * DMODEL))[tid];
  float4 c = ((const float4*)(res + (long)r * DMODEL))[tid];
  a.x += c.x; a.y += c.y; a.z += c.z; a.w += c.w;
  float s  = a.x + a.y + a.z + a.w;
  float ss = a.x * a.x + a.y * a.y + a.z * a.z + a.w * a.w;
  float2 tot = block_reduce2(s, ss);
  float mean = tot.x * (1.0f / DMODEL);
  float var  = tot.y * (1.0f / DMODEL) - mean * mean;
  float inv  = 1.0f / sqrtf(var + 1e-5f);
  float4 gv = ((const float4*)g)[tid];
  float4 bv = ((const float4*)bb)[tid];
  float y0 = (a.x - mean) * inv * gv.x + bv.x;
  float y1 = (a.y - mean) * inv * gv.y + bv.y;
  float y2 = (a.z - mean) * inv * gv.z + bv.z;
  float y3 = (a.w - mean) * inv * gv.w + bv.w;
  float4 o = {y0, y1, y2, y3};
  ((float4*)(yf + (long)r * DMODEL))[tid] = o;
  f16x4 oh = {(f16)y0, (f16)y1, (f16)y2, (f16)y3};
  *(f16x4*)(yh + (long)r * DMODEL + tid * 4) = oh;
}

// ---------------- small GEMM: 64x64 tile, 3-buffer depth-2 prefetch (r12) ----------------
template <int HAS_BIAS, int RELU, int WF32, int WF16, int MASK>
__global__ __launch_bounds__(256) void gemm_sm(const f16* __restrict__ A,
                                               const f16* __restrict__ B,
                                               const float* __restrict__ bias,
                                               float* __restrict__ Cf,
                                               f16* __restrict__ Ch,
                                               int K, int N, long ldc, long coff,
                                               int mval, long zsA, long zsB, long zsC) {
  __shared__ __align__(16) f16 sA[3][2048];
  __shared__ __align__(16) f16 sB[3][2048];
  const int tid  = threadIdx.x;
  const int lane = tid & 63, wv = tid >> 6;
  const int wm = wv >> 1, wn = wv & 1;
  const int bm = blockIdx.y, bn = blockIdx.x;
  const int lr = lane & 15, lk = lane >> 4;

  A += (long)blockIdx.z * zsA;
  B += (long)blockIdx.z * zsB;
  Ch += (long)blockIdx.z * zsC;

  const f16* gA = A + ((long)(bm * 64 + (tid >> 2))) * K + (tid & 3) * 8;
  const f16* gB = B + ((long)(bn * 64 + (tid >> 2))) * K + (tid & 3) * 8;

  const int aoff = (wm * 32 + lr) * 32 + lk * 8;
  const int boff = (wn * 32 + lr) * 32 + lk * 8;

  f32x4 acc[2][2] = {};

#define SSTAGE(buf, kt)                                \
  gld_lds16(gA + (long)(kt) * 32, &sA[buf][tid * 8]);  \
  gld_lds16(gB + (long)(kt) * 32, &sB[buf][tid * 8]);

  const int nk = K >> 5;
  SSTAGE(0, 0);
  SSTAGE(1, 1);

  int cur = 0, stg = 2;
  for (int kt = 0; kt < nk; ++kt) {
    if (kt + 1 < nk) { VM2; } else { VM0; }
    BAR;
    if (kt + 2 < nk) { SSTAGE(stg, kt + 2); }
    f16x8 af0 = *(const f16x8*)&sA[cur][aoff];
    f16x8 af1 = *(const f16x8*)&sA[cur][aoff + 512];
    f16x8 bf0 = *(const f16x8*)&sB[cur][boff];
    f16x8 bf1 = *(const f16x8*)&sB[cur][boff + 512];
    acc[0][0] = MFMA16(af0, bf0, acc[0][0]);
    acc[0][1] = MFMA16(af0, bf1, acc[0][1]);
    acc[1][0] = MFMA16(af1, bf0, acc[1][0]);
    acc[1][1] = MFMA16(af1, bf1, acc[1][1]);
    cur = cur == 2 ? 0 : cur + 1;
    stg = stg == 2 ? 0 : stg + 1;
  }
#undef SSTAGE

  const int row0 = bm * 64 + wm * 32 + lk * 4;
  const int col0 = bn * 64 + wn * 32 + lr;
  #pragma unroll
  for (int mi = 0; mi < 2; ++mi) {
    #pragma unroll
    for (int ni = 0; ni < 2; ++ni) {
      int col = col0 + ni * 16;
      float bs = HAS_BIAS ? bias[col] : 0.0f;
      #pragma unroll
      for (int rg = 0; rg < 4; ++rg) {
        int row = row0 + mi * 16 + rg;
        if (!MASK || row < mval) {
          float v = acc[mi][ni][rg] + bs;
          if (RELU) v = v > 0.0f ? v : 0.0f;
          if (WF32) Cf[(long)row * ldc + coff + col] = v;
          if (WF16) Ch[(long)row * N + col] = (f16)v;
        }
      }
    }
  }
}

// ---------------- mega logits GEMM: M=6144, BM=512 x BN=128, deep-M tiles ----------------
// B re-read factor 24 -> 12 (768 MB); trio-pair XCD mapping: XCD pair (2x,2x+1)
// shares bm-trio {3x..3x+2} (3 MB A, L2-resident), splits bn range 125/125;
// each 128-row B panel is read by exactly 3 consecutive blocks on ONE XCD
// (L2-shared) -> L3-level B traffic toward 4 x 64 MB.
// BK=32, 3-slot ring (A 3x32KB + B 3x8KB = 120 KB), prefetch distance 2.
// 5 loads/thread/tile (A:4 at P1, B:1 at P2). Ledger: end-of-tile in-flight =
// t+1(5) + t+2(5) = 10; vmcnt(5) retires exactly t+1; BAR publishes. Slot
// (t+2)%3 = (t-1)%3 anti-overwrite proven by t-1's end-BAR. Prologue stages
// t0,t1 (10), vmcnt(5)+BAR. Wrap-stage keeps ledger uniform; VM0 drains.
// 2 fine phases: {stage || ds_read frags -> lgkmcnt(0)+sched_barrier ->
// setprio 16xMFMA}. Chunk-XOR LDS swizzle (verified 0 conflicts).
__global__ __launch_bounds__(512, 1) void gemm512x(const f16* __restrict__ A,
                                                   const f16* __restrict__ B,
                                                   float* __restrict__ C) {
  __shared__ __align__(16) f16 sA[3][16384];  // 512 rows x 32 f16 per slot
  __shared__ __align__(16) f16 sB[3][4096];   // 128 rows x 32 f16 per slot
  const int K = 1024;
  const int tid = threadIdx.x;
  const int lane = tid & 63;
  const int wv = tid >> 6;                 // 0..7
  const int wm = wv >> 1, wn = wv & 1;     // wave tile 128x64
  const int lr = lane & 15, lk = lane >> 4;

  // trio-pair XCD mapping: 3000 blocks = 8 XCDs x 375 (3 bm x 125 bn each).
  const int flat = blockIdx.y * 125 + blockIdx.x;
  const int xcd = flat & 7, i = flat >> 3;      // i 0..374
  const int bm = (xcd >> 1) * 3 + (i % 3);      // 0..11 (trio per XCD pair)
  const int bn = (xcd & 1) * 125 + (i / 3);     // 0..249

  const int srow = tid >> 2;                         // 0..127
  const int schunk = (tid & 3) ^ ((tid >> 3) & 3);   // pre-swizzled source chunk
  const f16* gA = A + (long)(bm * 512 + srow) * K + schunk * 8;
  const f16* gB = B + (long)(bn * 128 + srow) * K + schunk * 8;
  const long rstep = 128L * (long)K;

  const int swz = ((lr >> 1) & 3) << 3;              // lane-constant read XOR
  const int aoff = (((wm * 128 + lr) * 32) + lk * 8) ^ swz;  // + mi*512
  const int boff = (((wn * 64  + lr) * 32) + lk * 8) ^ swz;  // + ni*512

  f32x4 acc[8][4] = {};

#define STG_A(s, kt)                                                        \
  gld_lds16(gA + (long)(kt) * 32,             &sA[s][tid * 8]);             \
  gld_lds16(gA + (long)(kt) * 32 + rstep,     &sA[s][tid * 8 + 4096]);      \
  gld_lds16(gA + (long)(kt) * 32 + 2 * rstep, &sA[s][tid * 8 + 8192]);      \
  gld_lds16(gA + (long)(kt) * 32 + 3 * rstep, &sA[s][tid * 8 + 12288]);
#define STG_B(s, kt)                                                        \
  gld_lds16(gB + (long)(kt) * 32, &sB[s][tid * 8]);

  // prologue: tiles 0,1 (10 loads); vmcnt(5) retires tile 0; BAR publishes.
  STG_A(0, 0) STG_B(0, 0)
  STG_A(1, 1) STG_B(1, 1)
  VM5; BAR;

  const int nt = 32;  // K / 32
  for (int t = 0; t < nt; ++t) {
    const int slot = t % 3;
    const int s2 = (slot >= 1) ? slot - 1 : 2;              // (t+2) % 3
    const int kt2 = (t + 2 < nt) ? (t + 2) : (t + 2 - nt);  // wrap keeps ledger uniform
    f16x8 af[8], bf[4];

    // ---- P1: mi 0-3 ----
    STG_A(s2, kt2)
    #pragma unroll
    for (int i2 = 0; i2 < 4; ++i2) af[i2] = *(const f16x8*)&sA[slot][aoff + i2 * 512];
    #pragma unroll
    for (int j = 0; j < 4; ++j) bf[j] = *(const f16x8*)&sB[slot][boff + j * 512];
    LGKM0; SCHED0;
    __builtin_amdgcn_s_setprio(1);
    #pragma unroll
    for (int i2 = 0; i2 < 4; ++i2)
      #pragma unroll
      for (int j = 0; j < 4; ++j)
        acc[i2][j] = MFMA16(af[i2], bf[j], acc[i2][j]);
    __builtin_amdgcn_s_setprio(0);

    // ---- P2: mi 4-7 ----
    STG_B(s2, kt2)
    #pragma unroll
    for (int i2 = 0; i2 < 4; ++i2) af[i2 + 4] = *(const f16x8*)&sA[slot][aoff + (i2 + 4) * 512];
    LGKM0; SCHED0;
    __builtin_amdgcn_s_setprio(1);
    #pragma unroll
    for (int i2 = 0; i2 < 4; ++i2)
      #pragma unroll
      for (int j = 0; j < 4; ++j)
        acc[i2 + 4][j] = MFMA16(af[i2 + 4], bf[j], acc[i2 + 4][j]);
    __builtin_amdgcn_s_setprio(0);

    VM5;   // retires tile t+1's 5 loads (leaves t+2's 5 in flight)
    BAR;   // publishes tile t+1; proves slot (t+2)%3 readable for restage
  }
  VM0;  // drain wrap stages

  // epilogue: head = bm>>2 (512 rows/tile, 4 tiles/head; no head straddle)
  const int head = bm >> 2;
  const long coff = (long)head * 32000;
  const int row0 = (bm & 3) * 512 + wm * 128 + lk * 4;
  const int col0 = bn * 128 + wn * 64 + lr;
  #pragma unroll
  for (int mi = 0; mi < 8; ++mi) {
    #pragma unroll
    for (int ni = 0; ni < 4; ++ni) {
      int col = col0 + ni * 16;
      #pragma unroll
      for (int rg = 0; rg < 4; ++rg) {
        int row = row0 + mi * 16 + rg;
        if (row < MROWS) C[(long)row * 96000 + coff + col] = acc[mi][ni][rg];
      }
    }
  }
#undef STG_A
#undef STG_B
}

// ---------------- host-side orchestration ----------------
extern "C" void kernel_launch(void* const* d_in, const int* in_sizes, int n_in,
                              void* d_out, int out_size, void* d_ws, size_t ws_size,
                              hipStream_t stream) {
  const int*   tok   = (const int*)d_in[0];
  const float* embed = (const float*)d_in[1];
  auto P = [&](int k, int j) { return (const float*)d_in[2 + k * 14 + j]; };
  float* out = (float*)d_out;

  char* w = (char*)d_ws;
  auto alloc = [&](size_t bytes) { char* p = w; w += bytes; return p; };
  const size_t MM = (size_t)1024 * 1024;

  f16* embed_h = (f16*)alloc((size_t)32000 * 1024 * 2);
  f16* Wo_all  = (f16*)alloc(3 * MM * 2);
  f16* Wvo_all = (f16*)alloc(3 * MM * 2);
  f16 *Wm_h[3], *W1_h[3], *W2_h[3];
  for (int k = 0; k < 3; ++k) {
    Wm_h[k]  = (f16*)alloc((size_t)1024 * 2048 * 2);
    W1_h[k]  = (f16*)alloc((size_t)2048 * 1024 * 2);
    W2_h[k]  = (f16*)alloc((size_t)1024 * 2048 * 2);
  }
  float* hprev  = (float*)alloc((size_t)MPAD * 1024 * 4);
  f16*   h_all  = (f16*)alloc((size_t)3 * MPAD * 1024 * 2);
  f16*   merged = (f16*)alloc((size_t)MPAD * 2048 * 2);
  float* xf     = (float*)alloc((size_t)MPAD * 1024 * 4);
  f16*   xh     = (f16*)alloc((size_t)MPAD * 1024 * 2);
  f16*   ff1    = (f16*)alloc((size_t)MPAD * 2048 * 2);
  float* t1     = (float*)alloc((size_t)MPAD * 1024 * 4);
  float* bvo    = (float*)alloc(3 * 1024 * 4);
  f16* WvT_all = merged;  // scratch overlay (merged written later, stream-ordered)

  // ---- prep ----
  conv_f32_f16<<<16000, 256, 0, stream>>>(embed, embed_h, (long)32000 * 1024);

  ConvArgs ca;
  for (int k = 0; k < 3; ++k) {
    ca.s[k*4+0] = P(k, 0); ca.d[k*4+0] = Wm_h[k];        ca.n[k*4+0] = (long)1024 * 2048;
    ca.s[k*4+1] = P(k, 4); ca.d[k*4+1] = Wo_all + k*MM;  ca.n[k*4+1] = (long)1024 * 1024;
    ca.s[k*4+2] = P(k, 6); ca.d[k*4+2] = W1_h[k];        ca.n[k*4+2] = (long)2048 * 1024;
    ca.s[k*4+3] = P(k, 8); ca.d[k*4+3] = W2_h[k];        ca.n[k*4+3] = (long)1024 * 2048;
  }
  conv_many<<<dim3(1024, 12), 256, 0, stream>>>(ca);

  TpArgs ta;
  for (int k = 0; k < 3; ++k) { ta.s[k] = P(k, 2); ta.d[k] = WvT_all + k * MM; }
  transpose3<<<dim3(32, 32, 3), 256, 0, stream>>>(ta);

  gemm_sm<0, 0, 0, 1, 0><<<dim3(16, 16, 3), 256, 0, stream>>>(
      Wo_all, WvT_all, nullptr, nullptr, Wvo_all, 1024, 1024, 1024L, 0L, 1024,
      (long)MM, (long)MM, (long)MM);

  BvoArgs ba;
  for (int k = 0; k < 3; ++k) {
    ba.Wo[k] = P(k, 4); ba.bv[k] = P(k, 3); ba.bo[k] = P(k, 5); ba.out[k] = bvo + k * 1024;
  }
  make_bvo3<<<dim3(1024, 3), 64, 0, stream>>>(ba);

  // ---- 3 encoder chains (logits deferred to one mega GEMM) ----
  for (int k = 0; k < 3; ++k) {
    merge_rms<<<MROWS, 256, 0, stream>>>(hprev, embed, tok, merged, k + 1,
                                         k == 0 ? 0 : -1);
    gemm_sm<1, 0, 1, 1, 0><<<dim3(16, 32), 256, 0, stream>>>(
        merged, Wm_h[k], P(k, 1), xf, xh, 2048, 1024, 1024L, 0L, MROWS, 0L, 0L, 0L);
    gemm_sm<1, 0, 1, 0, 0><<<dim3(16, 32), 256, 0, stream>>>(
        xh, Wvo_all + k * MM, bvo + k * 1024, t1, nullptr, 1024, 1024, 1024L, 0L,
        MROWS, 0L, 0L, 0L);
    add_ln<<<MROWS, 256, 0, stream>>>(xf, t1, P(k, 10), P(k, 11), xf, xh);
    gemm_sm<1, 1, 0, 1, 0><<<dim3(32, 32), 256, 0, stream>>>(
        xh, W1_h[k], P(k, 7), nullptr, ff1, 1024, 2048, 2048L, 0L, MROWS, 0L, 0L, 0L);
    gemm_sm<1, 0, 1, 0, 0><<<dim3(16, 32), 256, 0, stream>>>(
        ff1, W2_h[k], P(k, 9), t1, nullptr, 2048, 1024, 1024L, 0L, MROWS, 0L, 0L, 0L);
    add_ln<<<MROWS, 256, 0, stream>>>(xf, t1, P(k, 12), P(k, 13), hprev,
                                      h_all + (size_t)k * MPAD * 1024);
  }

  // ---- one mega logits GEMM (BM=512 deep-M tiles) ----
  gemm512x<<<dim3(125, 24), 512, 0, stream>>>(h_all, embed_h, out);
}

// Round 17
// 963.623 us; speedup vs baseline: 1.0564x; 1.0564x over previous
//
#include <hip/hip_runtime.h>

// SimpleMTP: 3 sequential MTP heads on MI355X.
// f16 MFMA everywhere heavy; f32 residual/norms.
// Logits: r15 deep-ring kernel verbatim (best: 567us) - 256x256, BK=32,
//   4-slot ring distance-3, vmcnt(8)/tile, rectangle XCD swizzle, XOR LDS.
// Small GEMMs: 64x64 3-buffer depth-2 (r12 inner loop) + NEW XCD-slice
//   swizzle: XCD owns contiguous bm-slice (A 0.5-1MB L2-resident) x all bn;
//   per-XCD working set 2.5-5MB ~ L2 -> operand re-reads become L2 hits.
// Wv/Wo fused into Wvo = Wo@Wv (precomputed per call).

#define NPOS   509
#define MROWS  2036
#define MPAD   2048
#define DMODEL 1024

typedef _Float16 f16;
typedef _Float16 f16x8 __attribute__((ext_vector_type(8)));
typedef _Float16 f16x4 __attribute__((ext_vector_type(4)));
typedef float    f32x4 __attribute__((ext_vector_type(4)));

#define MFMA16(a, b, c) __builtin_amdgcn_mfma_f32_16x16x32_f16(a, b, c, 0, 0, 0)
#define VM0   asm volatile("s_waitcnt vmcnt(0)" ::: "memory")
#define VM2   asm volatile("s_waitcnt vmcnt(2)" ::: "memory")
#define VM8   asm volatile("s_waitcnt vmcnt(8)" ::: "memory")
#define LGKM0 asm volatile("s_waitcnt lgkmcnt(0)" ::: "memory")
#define SCHED0 __builtin_amdgcn_sched_barrier(0)
#define BAR   asm volatile("s_barrier" ::: "memory")

__device__ __forceinline__ void gld_lds16(const void* g, void* l) {
  __builtin_amdgcn_global_load_lds(
      (const __attribute__((address_space(1))) void*)g,
      (__attribute__((address_space(3))) void*)l, 16, 0, 0);
}

// ---------------- f32 -> f16 convert: embed ----------------
__global__ __launch_bounds__(256) void conv_f32_f16(const float* __restrict__ src,
                                                    f16* __restrict__ dst, long n) {
  long i = ((long)blockIdx.x * 256 + threadIdx.x) * 8;
  if (i + 8 <= n) {
    float4 a = *(const float4*)(src + i);
    float4 b = *(const float4*)(src + i + 4);
    f16x8 o = {(f16)a.x, (f16)a.y, (f16)a.z, (f16)a.w,
               (f16)b.x, (f16)b.y, (f16)b.z, (f16)b.w};
    *(f16x8*)(dst + i) = o;
  }
}

// ---------------- batched weight conversion (12 tensors) ----------------
struct ConvArgs { const float* s[12]; f16* d[12]; long n[12]; };
__global__ __launch_bounds__(256) void conv_many(ConvArgs a) {
  int t = blockIdx.y;
  long i = ((long)blockIdx.x * 256 + threadIdx.x) * 8;
  if (i + 8 <= a.n[t]) {
    const float* src = a.s[t];
    float4 x = *(const float4*)(src + i);
    float4 y = *(const float4*)(src + i + 4);
    f16x8 o = {(f16)x.x, (f16)x.y, (f16)x.z, (f16)x.w,
               (f16)y.x, (f16)y.y, (f16)y.z, (f16)y.w};
    *(f16x8*)(a.d[t] + i) = o;
  }
}

// ---------------- batched 1024x1024 transpose f32->f16 (Wv -> WvT) ----------------
struct TpArgs { const float* s[3]; f16* d[3]; };
__global__ __launch_bounds__(256) void transpose3(TpArgs a) {
  __shared__ float t[32][33];
  int h = blockIdx.z;
  int bx = blockIdx.x * 32, by = blockIdx.y * 32;
  int tx = threadIdx.x & 31, ty = threadIdx.x >> 5;
  const float* src = a.s[h];
  f16* dst = a.d[h];
  #pragma unroll
  for (int r = 0; r < 32; r += 8)
    t[ty + r][tx] = src[(long)(by + ty + r) * 1024 + bx + tx];
  __syncthreads();
  #pragma unroll
  for (int r = 0; r < 32; r += 8)
    dst[(long)(bx + ty + r) * 1024 + by + tx] = (f16)t[tx][ty + r];
}

// ---------------- bvo = Wo @ bv + bo (batched over heads) ----------------
struct BvoArgs { const float* Wo[3]; const float* bv[3]; const float* bo[3]; float* out[3]; };
__global__ __launch_bounds__(64) void make_bvo3(BvoArgs a) {
  int h = blockIdx.y, r = blockIdx.x, l = threadIdx.x;
  const float* Wo = a.Wo[h];
  const float* bv = a.bv[h];
  float s = 0.0f;
  for (int k = l; k < 1024; k += 64) s += Wo[(long)r * 1024 + k] * bv[k];
  #pragma unroll
  for (int off = 32; off > 0; off >>= 1) s += __shfl_xor(s, off);
  if (l == 0) a.out[h][r] = s + a.bo[h][r];
}

__device__ __forceinline__ float2 block_reduce2(float a, float b) {
  #pragma unroll
  for (int off = 32; off > 0; off >>= 1) {
    a += __shfl_xor(a, off);
    b += __shfl_xor(b, off);
  }
  __shared__ float2 red[4];
  int wv = threadIdx.x >> 6;
  if ((threadIdx.x & 63) == 0) red[wv] = make_float2(a, b);
  __syncthreads();
  float2 r0 = red[0], r1 = red[1], r2 = red[2], r3 = red[3];
  return make_float2(r0.x + r1.x + r2.x + r3.x, r0.y + r1.y + r2.y + r3.y);
}

// ---------------- merged = [rmsnorm(h_prev), rmsnorm(tok)] ----------------
__global__ __launch_bounds__(256) void merge_rms(const float* __restrict__ hprev,
                                                 const float* __restrict__ embed,
                                                 const int* __restrict__ tok,
                                                 f16* __restrict__ merged, int koff,
                                                 int hsel) {
  int r = blockIdx.x;
  int b = r / NPOS, t = r - b * NPOS;
  int tid = threadIdx.x;
  const float* hrow = (hsel >= 0)
      ? embed + (long)tok[b * 512 + t + hsel] * DMODEL
      : hprev + (long)r * DMODEL;
  float4 hv = ((const float4*)hrow)[tid];
  float4 tv = ((const float4*)(embed + (long)tok[b * 512 + t + koff] * DMODEL))[tid];
  float sh = hv.x * hv.x + hv.y * hv.y + hv.z * hv.z + hv.w * hv.w;
  float st = tv.x * tv.x + tv.y * tv.y + tv.z * tv.z + tv.w * tv.w;
  float2 tot = block_reduce2(sh, st);
  float ih = 1.0f / sqrtf(tot.x * (1.0f / DMODEL) + 1e-8f);
  float it = 1.0f / sqrtf(tot.y * (1.0f / DMODEL) + 1e-8f);
  f16x4 oh = {(f16)(hv.x * ih), (f16)(hv.y * ih), (f16)(hv.z * ih), (f16)(hv.w * ih)};
  f16x4 ot = {(f16)(tv.x * it), (f16)(tv.y * it), (f16)(tv.z * it), (f16)(tv.w * it)};
  *(f16x4*)(merged + (long)r * 2048 + tid * 4) = oh;
  *(f16x4*)(merged + (long)r * 2048 + 1024 + tid * 4) = ot;
}

// ---------------- y = LN(x + res) * g + b ----------------
__global__ __launch_bounds__(256) void add_ln(const float* __restrict__ x,
                                              const float* __restrict__ res,
                                              const float* __restrict__ g,
                                              const float* __restrict__ bb,
                                              float* __restrict__ yf,
                                              f16* __restrict__ yh) {
  int r = blockIdx.x, tid = threadIdx.x;
  float4 a = ((const float4*)(x + (long)r * DMODEL))[tid];
  float4 c = ((const float4*)(res + (long)r * DMODEL))[tid];
  a.x += c.x; a.y += c.y; a.z += c.z; a.w += c.w;
  float s  = a.x + a.y + a.z + a.w;
  float ss = a.x * a.x + a.y * a.y + a.z * a.z + a.w * a.w;
  float2 tot = block_reduce2(s, ss);
  float mean = tot.x * (1.0f / DMODEL);
  float var  = tot.y * (1.0f / DMODEL) - mean * mean;
  float inv  = 1.0f / sqrtf(var + 1e-5f);
  float4 gv = ((const float4*)g)[tid];
  float4 bv = ((const float4*)bb)[tid];
  float y0 = (a.x - mean) * inv * gv.x + bv.x;
  float y1 = (a.y - mean) * inv * gv.y + bv.y;
  float y2 = (a.z - mean) * inv * gv.z + bv.z;
  float y3 = (a.w - mean) * inv * gv.w + bv.w;
  float4 o = {y0, y1, y2, y3};
  ((float4*)(yf + (long)r * DMODEL))[tid] = o;
  f16x4 oh = {(f16)y0, (f16)y1, (f16)y2, (f16)y3};
  *(f16x4*)(yh + (long)r * DMODEL + tid * 4) = oh;
}

// ---------------- small GEMM: 64x64, 3-buffer depth-2, XCD-slice swizzle ----------------
// 1-D grid (nbm*nbn blocks, z = batch). XCD x owns bm in [x*nbm/8,(x+1)*nbm/8)
// crossed with ALL bn: A-slice (nbm/8 * 64 rows, 0.5-1 MB) is read once per
// XCD then L2-resident; B re-reads hit L2 (per-XCD working set 2.5-5 MB).
// Bijective: j = flat>>3 -> (bm-within-slice, bn). Requires nbm%8==0.
// Inner loop = r12's proven 3-buffer depth-2 schedule, unchanged.
template <int HAS_BIAS, int RELU, int WF32, int WF16, int MASK>
__global__ __launch_bounds__(256) void gemm_sm(const f16* __restrict__ A,
                                               const f16* __restrict__ B,
                                               const float* __restrict__ bias,
                                               float* __restrict__ Cf,
                                               f16* __restrict__ Ch,
                                               int K, int N, long ldc, long coff,
                                               int mval, long zsA, long zsB, long zsC,
                                               int nbm) {
  __shared__ __align__(16) f16 sA[3][2048];
  __shared__ __align__(16) f16 sB[3][2048];
  const int tid  = threadIdx.x;
  const int lane = tid & 63, wv = tid >> 6;
  const int wm = wv >> 1, wn = wv & 1;
  const int lr = lane & 15, lk = lane >> 4;

  // XCD-slice swizzle
  const int flat = blockIdx.x;
  const int xcd = flat & 7, j = flat >> 3;
  const int mb8 = nbm >> 3;
  const int bm = xcd * mb8 + (j % mb8);
  const int bn = j / mb8;

  A += (long)blockIdx.z * zsA;
  B += (long)blockIdx.z * zsB;
  Ch += (long)blockIdx.z * zsC;

  const f16* gA = A + ((long)(bm * 64 + (tid >> 2))) * K + (tid & 3) * 8;
  const f16* gB = B + ((long)(bn * 64 + (tid >> 2))) * K + (tid & 3) * 8;

  const int aoff = (wm * 32 + lr) * 32 + lk * 8;
  const int boff = (wn * 32 + lr) * 32 + lk * 8;

  f32x4 acc[2][2] = {};

#define SSTAGE(buf, kt)                                \
  gld_lds16(gA + (long)(kt) * 32, &sA[buf][tid * 8]);  \
  gld_lds16(gB + (long)(kt) * 32, &sB[buf][tid * 8]);

  const int nk = K >> 5;
  SSTAGE(0, 0);
  SSTAGE(1, 1);

  int cur = 0, stg = 2;
  for (int kt = 0; kt < nk; ++kt) {
    if (kt + 1 < nk) { VM2; } else { VM0; }
    BAR;
    if (kt + 2 < nk) { SSTAGE(stg, kt + 2); }
    f16x8 af0 = *(const f16x8*)&sA[cur][aoff];
    f16x8 af1 = *(const f16x8*)&sA[cur][aoff + 512];
    f16x8 bf0 = *(const f16x8*)&sB[cur][boff];
    f16x8 bf1 = *(const f16x8*)&sB[cur][boff + 512];
    acc[0][0] = MFMA16(af0, bf0, acc[0][0]);
    acc[0][1] = MFMA16(af0, bf1, acc[0][1]);
    acc[1][0] = MFMA16(af1, bf0, acc[1][0]);
    acc[1][1] = MFMA16(af1, bf1, acc[1][1]);
    cur = cur == 2 ? 0 : cur + 1;
    stg = stg == 2 ? 0 : stg + 1;
  }
#undef SSTAGE

  const int row0 = bm * 64 + wm * 32 + lk * 4;
  const int col0 = bn * 64 + wn * 32 + lr;
  #pragma unroll
  for (int mi = 0; mi < 2; ++mi) {
    #pragma unroll
    for (int ni = 0; ni < 2; ++ni) {
      int col = col0 + ni * 16;
      float bs = HAS_BIAS ? bias[col] : 0.0f;
      #pragma unroll
      for (int rg = 0; rg < 4; ++rg) {
        int row = row0 + mi * 16 + rg;
        if (!MASK || row < mval) {
          float v = acc[mi][ni][rg] + bs;
          if (RELU) v = v > 0.0f ? v : 0.0f;
          if (WF32) Cf[(long)row * ldc + coff + col] = v;
          if (WF16) Ch[(long)row * N + col] = (f16)v;
        }
      }
    }
  }
}

// ---------------- mega logits GEMM: M=6144, 256x256 tile, deep ring (r15) ----------------
__global__ __launch_bounds__(512, 2) void gemm256x(const f16* __restrict__ A,
                                                   const f16* __restrict__ B,
                                                   float* __restrict__ C) {
  __shared__ __align__(16) f16 sA[4][8192];
  __shared__ __align__(16) f16 sB[4][8192];
  const int K = 1024;
  const int tid = threadIdx.x;
  const int lane = tid & 63;
  const int wv = tid >> 6;
  const int wm = wv >> 2, wn = wv & 3;
  const int lr = lane & 15, lk = lane >> 4;

  const int flat = blockIdx.y * 125 + blockIdx.x;
  const int xcd = flat & 7, i = flat >> 3;
  const int grp = i / 15, w = i % 15;
  const int bm = xcd * 3 + (w % 3);
  const int bn = grp * 5 + (w / 3);

  const int srow = tid >> 2;
  const int schunk = (tid & 3) ^ ((tid >> 3) & 3);
  const f16* gA = A + (long)(bm * 256 + srow) * K + schunk * 8;
  const f16* gB = B + (long)(bn * 256 + srow) * K + schunk * 8;
  const long rstep = 128L * (long)K;

  const int swz = ((lr >> 1) & 3) << 3;
  const int aoff = (((wm * 128 + lr) * 32) + lk * 8) ^ swz;
  const int boff = (((wn * 64  + lr) * 32) + lk * 8) ^ swz;

  f32x4 acc[8][4] = {};

#define STG_A(s, kt)                                                     \
  gld_lds16(gA + (long)(kt) * 32, &sA[s][tid * 8]);                      \
  gld_lds16(gA + (long)(kt) * 32 + rstep, &sA[s][tid * 8 + 4096]);
#define STG_B(s, kt)                                                     \
  gld_lds16(gB + (long)(kt) * 32, &sB[s][tid * 8]);                      \
  gld_lds16(gB + (long)(kt) * 32 + rstep, &sB[s][tid * 8 + 4096]);

  STG_A(0, 0) STG_B(0, 0)
  STG_A(1, 1) STG_B(1, 1)
  STG_A(2, 2) STG_B(2, 2)
  VM8; BAR;

  const int nt = 32;
  for (int t = 0; t < nt; ++t) {
    const int slot = t & 3, s3 = (t + 3) & 3;
    const int kt3 = (t + 3 < nt) ? (t + 3) : (t + 3 - nt);
    f16x8 af[8], bf[4];

    // ---- P1: mi 0-3 ----
    STG_A(s3, kt3)
    #pragma unroll
    for (int i2 = 0; i2 < 4; ++i2) af[i2] = *(const f16x8*)&sA[slot][aoff + i2 * 512];
    #pragma unroll
    for (int j = 0; j < 4; ++j) bf[j] = *(const f16x8*)&sB[slot][boff + j * 512];
    LGKM0; SCHED0;
    __builtin_amdgcn_s_setprio(1);
    #pragma unroll
    for (int i2 = 0; i2 < 4; ++i2)
      #pragma unroll
      for (int j = 0; j < 4; ++j)
        acc[i2][j] = MFMA16(af[i2], bf[j], acc[i2][j]);
    __builtin_amdgcn_s_setprio(0);

    // ---- P2: mi 4-7 ----
    STG_B(s3, kt3)
    #pragma unroll
    for (int i2 = 0; i2 < 4; ++i2) af[i2 + 4] = *(const f16x8*)&sA[slot][aoff + (i2 + 4) * 512];
    LGKM0; SCHED0;
    __builtin_amdgcn_s_setprio(1);
    #pragma unroll
    for (int i2 = 0; i2 < 4; ++i2)
      #pragma unroll
      for (int j = 0; j < 4; ++j)
        acc[i2 + 4][j] = MFMA16(af[i2 + 4], bf[j], acc[i2 + 4][j]);
    __builtin_amdgcn_s_setprio(0);

    VM8;
    BAR;
  }
  VM0;

  const int head = bm >> 3;
  const long coff = (long)head * 32000;
  const int row0 = (bm & 7) * 256 + wm * 128 + lk * 4;
  const int col0 = bn * 256 + wn * 64 + lr;
  #pragma unroll
  for (int mi = 0; mi < 8; ++mi) {
    #pragma unroll
    for (int ni = 0; ni < 4; ++ni) {
      int col = col0 + ni * 16;
      #pragma unroll
      for (int rg = 0; rg < 4; ++rg) {
        int row = row0 + mi * 16 + rg;
        if (row < MROWS) C[(long)row * 96000 + coff + col] = acc[mi][ni][rg];
      }
    }
  }
#undef STG_A
#undef STG_B
}

// ---------------- host-side orchestration ----------------
extern "C" void kernel_launch(void* const* d_in, const int* in_sizes, int n_in,
                              void* d_out, int out_size, void* d_ws, size_t ws_size,
                              hipStream_t stream) {
  const int*   tok   = (const int*)d_in[0];
  const float* embed = (const float*)d_in[1];
  auto P = [&](int k, int j) { return (const float*)d_in[2 + k * 14 + j]; };
  float* out = (float*)d_out;

  char* w = (char*)d_ws;
  auto alloc = [&](size_t bytes) { char* p = w; w += bytes; return p; };
  const size_t MM = (size_t)1024 * 1024;

  f16* embed_h = (f16*)alloc((size_t)32000 * 1024 * 2);
  f16* Wo_all  = (f16*)alloc(3 * MM * 2);
  f16* Wvo_all = (f16*)alloc(3 * MM * 2);
  f16 *Wm_h[3], *W1_h[3], *W2_h[3];
  for (int k = 0; k < 3; ++k) {
    Wm_h[k]  = (f16*)alloc((size_t)1024 * 2048 * 2);
    W1_h[k]  = (f16*)alloc((size_t)2048 * 1024 * 2);
    W2_h[k]  = (f16*)alloc((size_t)1024 * 2048 * 2);
  }
  float* hprev  = (float*)alloc((size_t)MPAD * 1024 * 4);
  f16*   h_all  = (f16*)alloc((size_t)3 * MPAD * 1024 * 2);
  f16*   merged = (f16*)alloc((size_t)MPAD * 2048 * 2);
  float* xf     = (float*)alloc((size_t)MPAD * 1024 * 4);
  f16*   xh     = (f16*)alloc((size_t)MPAD * 1024 * 2);
  f16*   ff1    = (f16*)alloc((size_t)MPAD * 2048 * 2);
  float* t1     = (float*)alloc((size_t)MPAD * 1024 * 4);
  float* bvo    = (float*)alloc(3 * 1024 * 4);
  f16* WvT_all = merged;  // scratch overlay (merged written later, stream-ordered)

  // ---- prep ----
  conv_f32_f16<<<16000, 256, 0, stream>>>(embed, embed_h, (long)32000 * 1024);

  ConvArgs ca;
  for (int k = 0; k < 3; ++k) {
    ca.s[k*4+0] = P(k, 0); ca.d[k*4+0] = Wm_h[k];        ca.n[k*4+0] = (long)1024 * 2048;
    ca.s[k*4+1] = P(k, 4); ca.d[k*4+1] = Wo_all + k*MM;  ca.n[k*4+1] = (long)1024 * 1024;
    ca.s[k*4+2] = P(k, 6); ca.d[k*4+2] = W1_h[k];        ca.n[k*4+2] = (long)2048 * 1024;
    ca.s[k*4+3] = P(k, 8); ca.d[k*4+3] = W2_h[k];        ca.n[k*4+3] = (long)1024 * 2048;
  }
  conv_many<<<dim3(1024, 12), 256, 0, stream>>>(ca);

  TpArgs ta;
  for (int k = 0; k < 3; ++k) { ta.s[k] = P(k, 2); ta.d[k] = WvT_all + k * MM; }
  transpose3<<<dim3(32, 32, 3), 256, 0, stream>>>(ta);

  // Wvo[k] = Wo[k] @ WvT[k]  (batched over z; nbm=16)
  gemm_sm<0, 0, 0, 1, 0><<<dim3(256, 1, 3), 256, 0, stream>>>(
      Wo_all, WvT_all, nullptr, nullptr, Wvo_all, 1024, 1024, 1024L, 0L, 1024,
      (long)MM, (long)MM, (long)MM, 16);

  BvoArgs ba;
  for (int k = 0; k < 3; ++k) {
    ba.Wo[k] = P(k, 4); ba.bv[k] = P(k, 3); ba.bo[k] = P(k, 5); ba.out[k] = bvo + k * 1024;
  }
  make_bvo3<<<dim3(1024, 3), 64, 0, stream>>>(ba);

  // ---- 3 encoder chains (logits deferred to one mega GEMM) ----
  for (int k = 0; k < 3; ++k) {
    merge_rms<<<MROWS, 256, 0, stream>>>(hprev, embed, tok, merged, k + 1,
                                         k == 0 ? 0 : -1);
    // x = merged @ Wmerge^T + bmerge   (nbm=32, nbn=16)
    gemm_sm<1, 0, 1, 1, 0><<<dim3(512), 256, 0, stream>>>(
        merged, Wm_h[k], P(k, 1), xf, xh, 2048, 1024, 1024L, 0L, MROWS,
        0L, 0L, 0L, 32);
    // attn = x @ Wvo^T + bvo
    gemm_sm<1, 0, 1, 0, 0><<<dim3(512), 256, 0, stream>>>(
        xh, Wvo_all + k * MM, bvo + k * 1024, t1, nullptr, 1024, 1024, 1024L, 0L,
        MROWS, 0L, 0L, 0L, 32);
    add_ln<<<MROWS, 256, 0, stream>>>(xf, t1, P(k, 10), P(k, 11), xf, xh);
    // ff1 = relu(x @ W1^T + b1)   (nbm=32, nbn=32)
    gemm_sm<1, 1, 0, 1, 0><<<dim3(1024), 256, 0, stream>>>(
        xh, W1_h[k], P(k, 7), nullptr, ff1, 1024, 2048, 2048L, 0L, MROWS,
        0L, 0L, 0L, 32);
    // ff = ff1 @ W2^T + b2
    gemm_sm<1, 0, 1, 0, 0><<<dim3(512), 256, 0, stream>>>(
        ff1, W2_h[k], P(k, 9), t1, nullptr, 2048, 1024, 1024L, 0L, MROWS,
        0L, 0L, 0L, 32);
    add_ln<<<MROWS, 256, 0, stream>>>(xf, t1, P(k, 12), P(k, 13), hprev,
                                      h_all + (size_t)k * MPAD * 1024);
  }

  // ---- one mega logits GEMM (r15 deep-ring) ----
  gemm256x<<<dim3(125, 24), 512, 0, stream>>>(h_all, embed_h, out);
}

// Round 18
// 961.627 us; speedup vs baseline: 1.0586x; 1.0021x over previous
//
#include <hip/hip_runtime.h>

// SimpleMTP: 3 sequential MTP heads on MI355X.
// f16 MFMA everywhere heavy; f32 residual/norms.
// Logits: r15 deep-ring (256x256, BK=32, 4-slot ring distance-3, vmcnt(8)/tile,
//   rectangle XCD swizzle, XOR LDS) MINUS the LGKM0/SCHED0 over-pinning:
//   compiler now fine-schedules ds_read->MFMA (lgkmcnt(N) interleave).
// Small GEMMs: 64x64 3-buffer depth-2 + XCD-slice swizzle (r17).
// NEW: add_ln_merge fuses ln2 epilogue with next head's merge_rms
//   (-2 launches, -16 MB traffic).
// Wv/Wo fused into Wvo = Wo@Wv (precomputed per call).

#define NPOS   509
#define MROWS  2036
#define MPAD   2048
#define DMODEL 1024

typedef _Float16 f16;
typedef _Float16 f16x8 __attribute__((ext_vector_type(8)));
typedef _Float16 f16x4 __attribute__((ext_vector_type(4)));
typedef float    f32x4 __attribute__((ext_vector_type(4)));

#define MFMA16(a, b, c) __builtin_amdgcn_mfma_f32_16x16x32_f16(a, b, c, 0, 0, 0)
#define VM0   asm volatile("s_waitcnt vmcnt(0)" ::: "memory")
#define VM2   asm volatile("s_waitcnt vmcnt(2)" ::: "memory")
#define VM8   asm volatile("s_waitcnt vmcnt(8)" ::: "memory")
#define BAR   asm volatile("s_barrier" ::: "memory")

__device__ __forceinline__ void gld_lds16(const void* g, void* l) {
  __builtin_amdgcn_global_load_lds(
      (const __attribute__((address_space(1))) void*)g,
      (__attribute__((address_space(3))) void*)l, 16, 0, 0);
}

// ---------------- f32 -> f16 convert: embed ----------------
__global__ __launch_bounds__(256) void conv_f32_f16(const float* __restrict__ src,
                                                    f16* __restrict__ dst, long n) {
  long i = ((long)blockIdx.x * 256 + threadIdx.x) * 8;
  if (i + 8 <= n) {
    float4 a = *(const float4*)(src + i);
    float4 b = *(const float4*)(src + i + 4);
    f16x8 o = {(f16)a.x, (f16)a.y, (f16)a.z, (f16)a.w,
               (f16)b.x, (f16)b.y, (f16)b.z, (f16)b.w};
    *(f16x8*)(dst + i) = o;
  }
}

// ---------------- batched weight conversion (12 tensors) ----------------
struct ConvArgs { const float* s[12]; f16* d[12]; long n[12]; };
__global__ __launch_bounds__(256) void conv_many(ConvArgs a) {
  int t = blockIdx.y;
  long i = ((long)blockIdx.x * 256 + threadIdx.x) * 8;
  if (i + 8 <= a.n[t]) {
    const float* src = a.s[t];
    float4 x = *(const float4*)(src + i);
    float4 y = *(const float4*)(src + i + 4);
    f16x8 o = {(f16)x.x, (f16)x.y, (f16)x.z, (f16)x.w,
               (f16)y.x, (f16)y.y, (f16)y.z, (f16)y.w};
    *(f16x8*)(a.d[t] + i) = o;
  }
}

// ---------------- batched 1024x1024 transpose f32->f16 (Wv -> WvT) ----------------
struct TpArgs { const float* s[3]; f16* d[3]; };
__global__ __launch_bounds__(256) void transpose3(TpArgs a) {
  __shared__ float t[32][33];
  int h = blockIdx.z;
  int bx = blockIdx.x * 32, by = blockIdx.y * 32;
  int tx = threadIdx.x & 31, ty = threadIdx.x >> 5;
  const float* src = a.s[h];
  f16* dst = a.d[h];
  #pragma unroll
  for (int r = 0; r < 32; r += 8)
    t[ty + r][tx] = src[(long)(by + ty + r) * 1024 + bx + tx];
  __syncthreads();
  #pragma unroll
  for (int r = 0; r < 32; r += 8)
    dst[(long)(bx + ty + r) * 1024 + by + tx] = (f16)t[tx][ty + r];
}

// ---------------- bvo = Wo @ bv + bo (batched over heads) ----------------
struct BvoArgs { const float* Wo[3]; const float* bv[3]; const float* bo[3]; float* out[3]; };
__global__ __launch_bounds__(64) void make_bvo3(BvoArgs a) {
  int h = blockIdx.y, r = blockIdx.x, l = threadIdx.x;
  const float* Wo = a.Wo[h];
  const float* bv = a.bv[h];
  float s = 0.0f;
  for (int k = l; k < 1024; k += 64) s += Wo[(long)r * 1024 + k] * bv[k];
  #pragma unroll
  for (int off = 32; off > 0; off >>= 1) s += __shfl_xor(s, off);
  if (l == 0) a.out[h][r] = s + a.bo[h][r];
}

// safe for repeated use within one kernel (trailing sync)
__device__ __forceinline__ float2 block_reduce2(float a, float b) {
  #pragma unroll
  for (int off = 32; off > 0; off >>= 1) {
    a += __shfl_xor(a, off);
    b += __shfl_xor(b, off);
  }
  __shared__ float2 red[4];
  int wv = threadIdx.x >> 6;
  if ((threadIdx.x & 63) == 0) red[wv] = make_float2(a, b);
  __syncthreads();
  float2 r0 = red[0], r1 = red[1], r2 = red[2], r3 = red[3];
  __syncthreads();
  return make_float2(r0.x + r1.x + r2.x + r3.x, r0.y + r1.y + r2.y + r3.y);
}

// ---------------- merged = [rmsnorm(h_prev), rmsnorm(tok)] (head 0) ----------------
__global__ __launch_bounds__(256) void merge_rms(const float* __restrict__ embed,
                                                 const int* __restrict__ tok,
                                                 f16* __restrict__ merged, int koff,
                                                 int hsel) {
  int r = blockIdx.x;
  int b = r / NPOS, t = r - b * NPOS;
  int tid = threadIdx.x;
  const float* hrow = embed + (long)tok[b * 512 + t + hsel] * DMODEL;
  float4 hv = ((const float4*)hrow)[tid];
  float4 tv = ((const float4*)(embed + (long)tok[b * 512 + t + koff] * DMODEL))[tid];
  float sh = hv.x * hv.x + hv.y * hv.y + hv.z * hv.z + hv.w * hv.w;
  float st = tv.x * tv.x + tv.y * tv.y + tv.z * tv.z + tv.w * tv.w;
  float2 tot = block_reduce2(sh, st);
  float ih = 1.0f / sqrtf(tot.x * (1.0f / DMODEL) + 1e-8f);
  float it = 1.0f / sqrtf(tot.y * (1.0f / DMODEL) + 1e-8f);
  f16x4 oh = {(f16)(hv.x * ih), (f16)(hv.y * ih), (f16)(hv.z * ih), (f16)(hv.w * ih)};
  f16x4 ot = {(f16)(tv.x * it), (f16)(tv.y * it), (f16)(tv.z * it), (f16)(tv.w * it)};
  *(f16x4*)(merged + (long)r * 2048 + tid * 4) = oh;
  *(f16x4*)(merged + (long)r * 2048 + 1024 + tid * 4) = ot;
}

// ---------------- y = LN(x + res) * g + b  (ln1: f32+f16 out) ----------------
__global__ __launch_bounds__(256) void add_ln(const float* __restrict__ x,
                                              const float* __restrict__ res,
                                              const float* __restrict__ g,
                                              const float* __restrict__ bb,
                                              float* __restrict__ yf,
                                              f16* __restrict__ yh) {
  int r = blockIdx.x, tid = threadIdx.x;
  float4 a = ((const float4*)(x + (long)r * DMODEL))[tid];
  float4 c = ((const float4*)(res + (long)r * DMODEL))[tid];
  a.x += c.x; a.y += c.y; a.z += c.z; a.w += c.w;
  float s  = a.x + a.y + a.z + a.w;
  float ss = a.x * a.x + a.y * a.y + a.z * a.z + a.w * a.w;
  float2 tot = block_reduce2(s, ss);
  float mean = tot.x * (1.0f / DMODEL);
  float var  = tot.y * (1.0f / DMODEL) - mean * mean;
  float inv  = 1.0f / sqrtf(var + 1e-5f);
  float4 gv = ((const float4*)g)[tid];
  float4 bv = ((const float4*)bb)[tid];
  float y0 = (a.x - mean) * inv * gv.x + bv.x;
  float y1 = (a.y - mean) * inv * gv.y + bv.y;
  float y2 = (a.z - mean) * inv * gv.z + bv.z;
  float y3 = (a.w - mean) * inv * gv.w + bv.w;
  float4 o = {y0, y1, y2, y3};
  ((float4*)(yf + (long)r * DMODEL))[tid] = o;
  f16x4 oh = {(f16)y0, (f16)y1, (f16)y2, (f16)y3};
  *(f16x4*)(yh + (long)r * DMODEL + tid * 4) = oh;
}

// ---------------- fused: h = LN(x+res); write h_all; merged[k+1] ----------------
// MERGE=1: also write merged = [rmsnorm(h), rmsnorm(embed[tok[t+koff]])].
template <int MERGE>
__global__ __launch_bounds__(256) void add_ln_merge(const float* __restrict__ x,
                                                    const float* __restrict__ res,
                                                    const float* __restrict__ g,
                                                    const float* __restrict__ bb,
                                                    f16* __restrict__ yh,
                                                    const float* __restrict__ embed,
                                                    const int* __restrict__ tok,
                                                    f16* __restrict__ merged,
                                                    int koff) {
  int r = blockIdx.x, tid = threadIdx.x;
  int b = r / NPOS, t = r - b * NPOS;
  float4 a = ((const float4*)(x + (long)r * DMODEL))[tid];
  float4 c = ((const float4*)(res + (long)r * DMODEL))[tid];
  a.x += c.x; a.y += c.y; a.z += c.z; a.w += c.w;
  float s  = a.x + a.y + a.z + a.w;
  float ss = a.x * a.x + a.y * a.y + a.z * a.z + a.w * a.w;
  float2 tot = block_reduce2(s, ss);
  float mean = tot.x * (1.0f / DMODEL);
  float var  = tot.y * (1.0f / DMODEL) - mean * mean;
  float inv  = 1.0f / sqrtf(var + 1e-5f);
  float4 gv = ((const float4*)g)[tid];
  float4 bv = ((const float4*)bb)[tid];
  float y0 = (a.x - mean) * inv * gv.x + bv.x;
  float y1 = (a.y - mean) * inv * gv.y + bv.y;
  float y2 = (a.z - mean) * inv * gv.z + bv.z;
  float y3 = (a.w - mean) * inv * gv.w + bv.w;
  f16x4 oh = {(f16)y0, (f16)y1, (f16)y2, (f16)y3};
  *(f16x4*)(yh + (long)r * DMODEL + tid * 4) = oh;
  if (MERGE) {
    float sy = y0 * y0 + y1 * y1 + y2 * y2 + y3 * y3;
    float4 tv = ((const float4*)(embed + (long)tok[b * 512 + t + koff] * DMODEL))[tid];
    float st = tv.x * tv.x + tv.y * tv.y + tv.z * tv.z + tv.w * tv.w;
    float2 t2 = block_reduce2(sy, st);
    float ih = 1.0f / sqrtf(t2.x * (1.0f / DMODEL) + 1e-8f);
    float it = 1.0f / sqrtf(t2.y * (1.0f / DMODEL) + 1e-8f);
    f16x4 mh = {(f16)(y0 * ih), (f16)(y1 * ih), (f16)(y2 * ih), (f16)(y3 * ih)};
    f16x4 mt = {(f16)(tv.x * it), (f16)(tv.y * it), (f16)(tv.z * it), (f16)(tv.w * it)};
    *(f16x4*)(merged + (long)r * 2048 + tid * 4) = mh;
    *(f16x4*)(merged + (long)r * 2048 + 1024 + tid * 4) = mt;
  }
}

// ---------------- small GEMM: 64x64, 3-buffer depth-2, XCD-slice swizzle ----------------
template <int HAS_BIAS, int RELU, int WF32, int WF16, int MASK>
__global__ __launch_bounds__(256) void gemm_sm(const f16* __restrict__ A,
                                               const f16* __restrict__ B,
                                               const float* __restrict__ bias,
                                               float* __restrict__ Cf,
                                               f16* __restrict__ Ch,
                                               int K, int N, long ldc, long coff,
                                               int mval, long zsA, long zsB, long zsC,
                                               int nbm) {
  __shared__ __align__(16) f16 sA[3][2048];
  __shared__ __align__(16) f16 sB[3][2048];
  const int tid  = threadIdx.x;
  const int lane = tid & 63, wv = tid >> 6;
  const int wm = wv >> 1, wn = wv & 1;
  const int lr = lane & 15, lk = lane >> 4;

  const int flat = blockIdx.x;
  const int xcd = flat & 7, j = flat >> 3;
  const int mb8 = nbm >> 3;
  const int bm = xcd * mb8 + (j % mb8);
  const int bn = j / mb8;

  A += (long)blockIdx.z * zsA;
  B += (long)blockIdx.z * zsB;
  Ch += (long)blockIdx.z * zsC;

  const f16* gA = A + ((long)(bm * 64 + (tid >> 2))) * K + (tid & 3) * 8;
  const f16* gB = B + ((long)(bn * 64 + (tid >> 2))) * K + (tid & 3) * 8;

  const int aoff = (wm * 32 + lr) * 32 + lk * 8;
  const int boff = (wn * 32 + lr) * 32 + lk * 8;

  f32x4 acc[2][2] = {};

#define SSTAGE(buf, kt)                                \
  gld_lds16(gA + (long)(kt) * 32, &sA[buf][tid * 8]);  \
  gld_lds16(gB + (long)(kt) * 32, &sB[buf][tid * 8]);

  const int nk = K >> 5;
  SSTAGE(0, 0);
  SSTAGE(1, 1);

  int cur = 0, stg = 2;
  for (int kt = 0; kt < nk; ++kt) {
    if (kt + 1 < nk) { VM2; } else { VM0; }
    BAR;
    if (kt + 2 < nk) { SSTAGE(stg, kt + 2); }
    f16x8 af0 = *(const f16x8*)&sA[cur][aoff];
    f16x8 af1 = *(const f16x8*)&sA[cur][aoff + 512];
    f16x8 bf0 = *(const f16x8*)&sB[cur][boff];
    f16x8 bf1 = *(const f16x8*)&sB[cur][boff + 512];
    acc[0][0] = MFMA16(af0, bf0, acc[0][0]);
    acc[0][1] = MFMA16(af0, bf1, acc[0][1]);
    acc[1][0] = MFMA16(af1, bf0, acc[1][0]);
    acc[1][1] = MFMA16(af1, bf1, acc[1][1]);
    cur = cur == 2 ? 0 : cur + 1;
    stg = stg == 2 ? 0 : stg + 1;
  }
#undef SSTAGE

  const int row0 = bm * 64 + wm * 32 + lk * 4;
  const int col0 = bn * 64 + wn * 32 + lr;
  #pragma unroll
  for (int mi = 0; mi < 2; ++mi) {
    #pragma unroll
    for (int ni = 0; ni < 2; ++ni) {
      int col = col0 + ni * 16;
      float bs = HAS_BIAS ? bias[col] : 0.0f;
      #pragma unroll
      for (int rg = 0; rg < 4; ++rg) {
        int row = row0 + mi * 16 + rg;
        if (!MASK || row < mval) {
          float v = acc[mi][ni][rg] + bs;
          if (RELU) v = v > 0.0f ? v : 0.0f;
          if (WF32) Cf[(long)row * ldc + coff + col] = v;
          if (WF16) Ch[(long)row * N + col] = (f16)v;
        }
      }
    }
  }
}

// ---------------- mega logits GEMM: M=6144, 256x256, deep ring ----------------
// r15 structure; LGKM0/SCHED0 removed: compiler emits fine-grained
// lgkmcnt(N) so early MFMAs overlap late ds_reads (m141 lesson: don't pin).
// BAR's memory clobber still orders ds_reads after the publish point.
__global__ __launch_bounds__(512, 2) void gemm256x(const f16* __restrict__ A,
                                                   const f16* __restrict__ B,
                                                   float* __restrict__ C) {
  __shared__ __align__(16) f16 sA[4][8192];
  __shared__ __align__(16) f16 sB[4][8192];
  const int K = 1024;
  const int tid = threadIdx.x;
  const int lane = tid & 63;
  const int wv = tid >> 6;
  const int wm = wv >> 2, wn = wv & 3;
  const int lr = lane & 15, lk = lane >> 4;

  const int flat = blockIdx.y * 125 + blockIdx.x;
  const int xcd = flat & 7, i = flat >> 3;
  const int grp = i / 15, w = i % 15;
  const int bm = xcd * 3 + (w % 3);
  const int bn = grp * 5 + (w / 3);

  const int srow = tid >> 2;
  const int schunk = (tid & 3) ^ ((tid >> 3) & 3);
  const f16* gA = A + (long)(bm * 256 + srow) * K + schunk * 8;
  const f16* gB = B + (long)(bn * 256 + srow) * K + schunk * 8;
  const long rstep = 128L * (long)K;

  const int swz = ((lr >> 1) & 3) << 3;
  const int aoff = (((wm * 128 + lr) * 32) + lk * 8) ^ swz;
  const int boff = (((wn * 64  + lr) * 32) + lk * 8) ^ swz;

  f32x4 acc[8][4] = {};

#define STG_A(s, kt)                                                     \
  gld_lds16(gA + (long)(kt) * 32, &sA[s][tid * 8]);                      \
  gld_lds16(gA + (long)(kt) * 32 + rstep, &sA[s][tid * 8 + 4096]);
#define STG_B(s, kt)                                                     \
  gld_lds16(gB + (long)(kt) * 32, &sB[s][tid * 8]);                      \
  gld_lds16(gB + (long)(kt) * 32 + rstep, &sB[s][tid * 8 + 4096]);

  STG_A(0, 0) STG_B(0, 0)
  STG_A(1, 1) STG_B(1, 1)
  STG_A(2, 2) STG_B(2, 2)
  VM8; BAR;

  const int nt = 32;
  for (int t = 0; t < nt; ++t) {
    const int slot = t & 3, s3 = (t + 3) & 3;
    const int kt3 = (t + 3 < nt) ? (t + 3) : (t + 3 - nt);
    f16x8 af[8], bf[4];

    // ---- P1: mi 0-3 ----
    STG_A(s3, kt3)
    #pragma unroll
    for (int i2 = 0; i2 < 4; ++i2) af[i2] = *(const f16x8*)&sA[slot][aoff + i2 * 512];
    #pragma unroll
    for (int j = 0; j < 4; ++j) bf[j] = *(const f16x8*)&sB[slot][boff + j * 512];
    __builtin_amdgcn_s_setprio(1);
    #pragma unroll
    for (int i2 = 0; i2 < 4; ++i2)
      #pragma unroll
      for (int j = 0; j < 4; ++j)
        acc[i2][j] = MFMA16(af[i2], bf[j], acc[i2][j]);
    __builtin_amdgcn_s_setprio(0);

    // ---- P2: mi 4-7 ----
    STG_B(s3, kt3)
    #pragma unroll
    for (int i2 = 0; i2 < 4; ++i2) af[i2 + 4] = *(const f16x8*)&sA[slot][aoff + (i2 + 4) * 512];
    __builtin_amdgcn_s_setprio(1);
    #pragma unroll
    for (int i2 = 0; i2 < 4; ++i2)
      #pragma unroll
      for (int j = 0; j < 4; ++j)
        acc[i2 + 4][j] = MFMA16(af[i2 + 4], bf[j], acc[i2 + 4][j]);
    __builtin_amdgcn_s_setprio(0);

    VM8;
    BAR;
  }
  VM0;

  const int head = bm >> 3;
  const long coff = (long)head * 32000;
  const int row0 = (bm & 7) * 256 + wm * 128 + lk * 4;
  const int col0 = bn * 256 + wn * 64 + lr;
  #pragma unroll
  for (int mi = 0; mi < 8; ++mi) {
    #pragma unroll
    for (int ni = 0; ni < 4; ++ni) {
      int col = col0 + ni * 16;
      #pragma unroll
      for (int rg = 0; rg < 4; ++rg) {
        int row = row0 + mi * 16 + rg;
        if (row < MROWS) C[(long)row * 96000 + coff + col] = acc[mi][ni][rg];
      }
    }
  }
#undef STG_A
#undef STG_B
}

// ---------------- host-side orchestration ----------------
extern "C" void kernel_launch(void* const* d_in, const int* in_sizes, int n_in,
                              void* d_out, int out_size, void* d_ws, size_t ws_size,
                              hipStream_t stream) {
  const int*   tok   = (const int*)d_in[0];
  const float* embed = (const float*)d_in[1];
  auto P = [&](int k, int j) { return (const float*)d_in[2 + k * 14 + j]; };
  float* out = (float*)d_out;

  char* w = (char*)d_ws;
  auto alloc = [&](size_t bytes) { char* p = w; w += bytes; return p; };
  const size_t MM = (size_t)1024 * 1024;

  f16* embed_h = (f16*)alloc((size_t)32000 * 1024 * 2);
  f16* Wo_all  = (f16*)alloc(3 * MM * 2);
  f16* Wvo_all = (f16*)alloc(3 * MM * 2);
  f16 *Wm_h[3], *W1_h[3], *W2_h[3];
  for (int k = 0; k < 3; ++k) {
    Wm_h[k]  = (f16*)alloc((size_t)1024 * 2048 * 2);
    W1_h[k]  = (f16*)alloc((size_t)2048 * 1024 * 2);
    W2_h[k]  = (f16*)alloc((size_t)1024 * 2048 * 2);
  }
  f16*   h_all  = (f16*)alloc((size_t)3 * MPAD * 1024 * 2);
  f16*   merged = (f16*)alloc((size_t)MPAD * 2048 * 2);
  float* xf     = (float*)alloc((size_t)MPAD * 1024 * 4);
  f16*   xh     = (f16*)alloc((size_t)MPAD * 1024 * 2);
  f16*   ff1    = (f16*)alloc((size_t)MPAD * 2048 * 2);
  float* t1     = (float*)alloc((size_t)MPAD * 1024 * 4);
  float* bvo    = (float*)alloc(3 * 1024 * 4);
  f16* WvT_all = (f16*)alloc(3 * MM * 2);

  // ---- prep ----
  conv_f32_f16<<<16000, 256, 0, stream>>>(embed, embed_h, (long)32000 * 1024);

  ConvArgs ca;
  for (int k = 0; k < 3; ++k) {
    ca.s[k*4+0] = P(k, 0); ca.d[k*4+0] = Wm_h[k];        ca.n[k*4+0] = (long)1024 * 2048;
    ca.s[k*4+1] = P(k, 4); ca.d[k*4+1] = Wo_all + k*MM;  ca.n[k*4+1] = (long)1024 * 1024;
    ca.s[k*4+2] = P(k, 6); ca.d[k*4+2] = W1_h[k];        ca.n[k*4+2] = (long)2048 * 1024;
    ca.s[k*4+3] = P(k, 8); ca.d[k*4+3] = W2_h[k];        ca.n[k*4+3] = (long)1024 * 2048;
  }
  conv_many<<<dim3(1024, 12), 256, 0, stream>>>(ca);

  TpArgs ta;
  for (int k = 0; k < 3; ++k) { ta.s[k] = P(k, 2); ta.d[k] = WvT_all + k * MM; }
  transpose3<<<dim3(32, 32, 3), 256, 0, stream>>>(ta);

  gemm_sm<0, 0, 0, 1, 0><<<dim3(256, 1, 3), 256, 0, stream>>>(
      Wo_all, WvT_all, nullptr, nullptr, Wvo_all, 1024, 1024, 1024L, 0L, 1024,
      (long)MM, (long)MM, (long)MM, 16);

  BvoArgs ba;
  for (int k = 0; k < 3; ++k) {
    ba.Wo[k] = P(k, 4); ba.bv[k] = P(k, 3); ba.bo[k] = P(k, 5); ba.out[k] = bvo + k * 1024;
  }
  make_bvo3<<<dim3(1024, 3), 64, 0, stream>>>(ba);

  // head 0 merged: both halves gathered from embed
  merge_rms<<<MROWS, 256, 0, stream>>>(embed, tok, merged, 1, 0);

  // ---- 3 encoder chains (logits deferred to one mega GEMM) ----
  for (int k = 0; k < 3; ++k) {
    gemm_sm<1, 0, 1, 1, 0><<<dim3(512), 256, 0, stream>>>(
        merged, Wm_h[k], P(k, 1), xf, xh, 2048, 1024, 1024L, 0L, MROWS,
        0L, 0L, 0L, 32);
    gemm_sm<1, 0, 1, 0, 0><<<dim3(512), 256, 0, stream>>>(
        xh, Wvo_all + k * MM, bvo + k * 1024, t1, nullptr, 1024, 1024, 1024L, 0L,
        MROWS, 0L, 0L, 0L, 32);
    add_ln<<<MROWS, 256, 0, stream>>>(xf, t1, P(k, 10), P(k, 11), xf, xh);
    gemm_sm<1, 1, 0, 1, 0><<<dim3(1024), 256, 0, stream>>>(
        xh, W1_h[k], P(k, 7), nullptr, ff1, 1024, 2048, 2048L, 0L, MROWS,
        0L, 0L, 0L, 32);
    gemm_sm<1, 0, 1, 0, 0><<<dim3(512), 256, 0, stream>>>(
        ff1, W2_h[k], P(k, 9), t1, nullptr, 2048, 1024, 1024L, 0L, MROWS,
        0L, 0L, 0L, 32);
    // h = LN(x + ff): write h_all[k]; for k<2 also produce merged for head k+1
    f16* hk = h_all + (size_t)k * MPAD * 1024;
    if (k < 2)
      add_ln_merge<1><<<MROWS, 256, 0, stream>>>(
          xf, t1, P(k, 12), P(k, 13), hk, embed, tok, merged, k + 2);
    else
      add_ln_merge<0><<<MROWS, 256, 0, stream>>>(
          xf, t1, P(k, 12), P(k, 13), hk, embed, tok, nullptr, 0);
  }

  // ---- one mega logits GEMM (deep-ring, unpinned scheduling) ----
  gemm256x<<<dim3(125, 24), 512, 0, stream>>>(h_all, embed_h, out);
}